// Round 7
// baseline (375.201 us; speedup 1.0000x reference)
//
#include <hip/hip_runtime.h>

#define NN 50000
#define NE 600000
#define DIM 128
#define NB_N 196   // ceil(50000/256)
#define NB_E 2344  // ceil(600000/256)
#define TILES 3125 // 50000/16
#define ROWW 136   // LDS row pitch in u16 (128 + 8 pad)
#define NEPAD (NE + 8 * NN + 64)  // rows padded to multiple of 8, min 8

typedef unsigned short u16;
typedef unsigned int u32;
typedef __attribute__((ext_vector_type(8))) short bf16x8;
typedef __attribute__((ext_vector_type(4))) float f32x4;

__device__ __forceinline__ u16 f2bf(float f) {
    u32 u = __builtin_bit_cast(u32, f);
    u32 r = (u + 0x7FFFu + ((u >> 16) & 1u)) >> 16;
    return (u16)r;
}
__device__ __forceinline__ float bflo(u32 w) { return __builtin_bit_cast(float, w << 16); }
__device__ __forceinline__ float bfhi(u32 w) { return __builtin_bit_cast(float, w & 0xffff0000u); }
__device__ __forceinline__ int pad8(int d) {
    int p = (d + 7) & ~7;
    return p < 8 ? 8 : p;
}

// ---- CSR build -------------------------------------------------------------

__global__ __launch_bounds__(256) void k_count(const int* __restrict__ ei,
                                               int* __restrict__ deg) {
    __shared__ int s64;
    if (threadIdx.x == 0) {
        int o = 0;
#pragma unroll
        for (int j = 0; j < 16; j++) o |= ei[2 * j + 1];  // int64 => high words 0
        s64 = (o == 0);
    }
    __syncthreads();
    int e = blockIdx.x * 256 + threadIdx.x;
    if (e >= NE) return;
    int d = s64 ? ei[2 * (NE + e)] : ei[NE + e];
    atomicAdd(&deg[d], 1);
}

// single-block scan: rp8 = exclusive scan of pad8(deg); dinv = rsqrt(deg+1)
__global__ __launch_bounds__(1024) void k_scan(const int* __restrict__ deg,
                                               int* __restrict__ rp8,
                                               float* __restrict__ dinv) {
    __shared__ int buf[1024];
    int t = threadIdx.x;
    int start = t * 49, end = min(start + 49, NN);
    int s = 0;
    for (int i = start; i < end; i++) s += pad8(deg[i]);
    buf[t] = s;
    __syncthreads();
    for (int off = 1; off < 1024; off <<= 1) {
        int x = (t >= off) ? buf[t - off] : 0;
        __syncthreads();
        buf[t] += x;
        __syncthreads();
    }
    int run = buf[t] - s;  // exclusive prefix
    for (int i = start; i < end; i++) {
        int d = deg[i];
        rp8[i] = run;
        dinv[i] = rsqrtf((float)(d + 1));  // +1 self loop
        run += pad8(d);
    }
    if (t == 1023) rp8[NN] = buf[1023];
}

// fill CSR (src only, 4 B) + secondary work: wcast, pad entries -> NN, zero
// sentinel rows of hwA/hwB
__global__ __launch_bounds__(256) void k_fill(const int* __restrict__ ei,
                                              const int* __restrict__ rp8,
                                              int* __restrict__ cursor,
                                              const int* __restrict__ deg,
                                              int* __restrict__ recs,
                                              const float* __restrict__ W0,
                                              const float* __restrict__ W1,
                                              const float* __restrict__ W2,
                                              u16* __restrict__ Wt,
                                              u16* __restrict__ hwA,
                                              u16* __restrict__ hwB) {
    __shared__ int s64;
    if (threadIdx.x == 0) {
        int o = 0;
#pragma unroll
        for (int j = 0; j < 16; j++) o |= ei[2 * j + 1];
        s64 = (o == 0);
    }
    __syncthreads();
    int e = blockIdx.x * 256 + threadIdx.x;
    if (e < NE) {
        int is64 = s64;
        int s = is64 ? ei[2 * e] : ei[e];
        int d = is64 ? ei[2 * (NE + e)] : ei[NE + e];
        int pos = rp8[d] + atomicAdd(&cursor[d], 1);
        recs[pos] = s;
    }
    // secondary roles
    int b = blockIdx.x;
    if (b < 192) {  // weight cast: Wt[layer][n][k] = bf16(W[layer][k][n])
        int idx = b * 256 + threadIdx.x;  // < 49152 = 3*16384
        int l = idx >> 14, rem = idx & 16383;
        int n = rem >> 7, k = rem & 127;
        const float* W = (l == 0) ? W0 : ((l == 1) ? W1 : W2);
        Wt[idx] = f2bf(W[k * 128 + n]);
    } else if (b < 388) {  // pad entries -> sentinel row NN
        int i = (b - 192) * 256 + threadIdx.x;
        if (i < NN) {
            int rp = rp8[i], d = deg[i], p = pad8(d);
            for (int j = d; j < p; j++) recs[rp + j] = NN;
        }
    } else if (b == 388) {  // zero sentinel rows (256 B each)
        if (threadIdx.x < 64) {
            ((u32*)(hwA + (size_t)NN * DIM))[threadIdx.x] = 0;
            ((u32*)(hwB + (size_t)NN * DIM))[threadIdx.x] = 0;
        }
    }
}

// ---- layer-1 GEMM: hw'[v] = dinv[v] * (bf16(x) @ W0) -----------------------
__global__ __launch_bounds__(256) void k_gemm_f32(const float* __restrict__ x,
                                                  const u16* __restrict__ Wt,
                                                  const float* __restrict__ dinv,
                                                  u16* __restrict__ hwb) {
    int lane = threadIdx.x & 63;
    int tile = blockIdx.x * 4 + (threadIdx.x >> 6);
    if (tile >= TILES) return;
    int r = lane & 15, q = lane >> 4;

    bf16x8 Bf[8][4];
#pragma unroll
    for (int nt = 0; nt < 8; nt++)
#pragma unroll
        for (int kc = 0; kc < 4; kc++)
            Bf[nt][kc] = *(const bf16x8*)(Wt + ((nt * 16 + r) << 7) + kc * 32 + q * 8);

    long rowbase = (long)tile * 16;
    bf16x8 Af[4];
#pragma unroll
    for (int kc = 0; kc < 4; kc++) {
        const float4* p = (const float4*)(x + (rowbase + r) * 128 + kc * 32 + q * 8);
        float4 t0 = p[0], t1 = p[1];
        bf16x8 a;
        a[0] = (short)f2bf(t0.x); a[1] = (short)f2bf(t0.y);
        a[2] = (short)f2bf(t0.z); a[3] = (short)f2bf(t0.w);
        a[4] = (short)f2bf(t1.x); a[5] = (short)f2bf(t1.y);
        a[6] = (short)f2bf(t1.z); a[7] = (short)f2bf(t1.w);
        Af[kc] = a;
    }

    float dv[4];
#pragma unroll
    for (int i = 0; i < 4; i++) dv[i] = dinv[rowbase + q * 4 + i];

#pragma unroll
    for (int nt = 0; nt < 8; nt++) {
        f32x4 acc = {0.f, 0.f, 0.f, 0.f};
#pragma unroll
        for (int kc = 0; kc < 4; kc++)
            acc = __builtin_amdgcn_mfma_f32_16x16x32_bf16(Af[kc], Bf[nt][kc], acc, 0, 0, 0);
#pragma unroll
        for (int i = 0; i < 4; i++)
            hwb[(rowbase + q * 4 + i) * 128 + nt * 16 + r] = f2bf(dv[i] * acc[i]);
    }
}

// ---- aggregation core: wave = 2 nodes interleaved; group g handles edges
// {e+2g, e+2g+1}; lane r=lane&15 holds feats 8r..8r+7. Pure adds (no norms):
// pads & clamped re-reads read sentinel row NN (zeros).
__device__ __forceinline__ void add8(float* a, uint4 u) {
    a[0] += bflo(u.x); a[1] += bfhi(u.x);
    a[2] += bflo(u.y); a[3] += bfhi(u.y);
    a[4] += bflo(u.z); a[5] += bfhi(u.z);
    a[6] += bflo(u.w); a[7] += bfhi(u.w);
}

__device__ __forceinline__ void agg_pair(const u16* __restrict__ hw,
                                         const int* __restrict__ rp8,
                                         const int* __restrict__ recs,
                                         int va, int vb, int g, int r,
                                         float* A, float* B) {
    uint4 sva = *(const uint4*)(hw + (size_t)va * DIM + r * 8);
    uint4 svb = *(const uint4*)(hw + (size_t)vb * DIM + r * 8);
    float m = (g == 0) ? 1.0f : 0.0f;  // self term counted once
    A[0] = m * bflo(sva.x); A[1] = m * bfhi(sva.x);
    A[2] = m * bflo(sva.y); A[3] = m * bfhi(sva.y);
    A[4] = m * bflo(sva.z); A[5] = m * bfhi(sva.z);
    A[6] = m * bflo(sva.w); A[7] = m * bfhi(sva.w);
    B[0] = m * bflo(svb.x); B[1] = m * bfhi(svb.x);
    B[2] = m * bflo(svb.y); B[3] = m * bfhi(svb.y);
    B[4] = m * bflo(svb.z); B[5] = m * bfhi(svb.z);
    B[6] = m * bflo(svb.w); B[7] = m * bfhi(svb.w);

    int ea = rp8[va], enda = rp8[va + 1];
    int eb = rp8[vb], endb = rp8[vb + 1];
    int2 qa = *(const int2*)(recs + ea + 2 * g);
    int2 qb = *(const int2*)(recs + eb + 2 * g);
    while (ea < enda || eb < endb) {
        int sa0 = (ea < enda) ? qa.x : NN;
        int sa1 = (ea < enda) ? qa.y : NN;
        int sb0 = (eb < endb) ? qb.x : NN;
        int sb1 = (eb < endb) ? qb.y : NN;
        uint4 ua0 = *(const uint4*)(hw + (size_t)(u32)sa0 * DIM + r * 8);
        uint4 ua1 = *(const uint4*)(hw + (size_t)(u32)sa1 * DIM + r * 8);
        uint4 ub0 = *(const uint4*)(hw + (size_t)(u32)sb0 * DIM + r * 8);
        uint4 ub1 = *(const uint4*)(hw + (size_t)(u32)sb1 * DIM + r * 8);
        ea += 8; eb += 8;
        int2 qa_n = *(const int2*)(recs + min(ea, enda - 8) + 2 * g);
        int2 qb_n = *(const int2*)(recs + min(eb, endb - 8) + 2 * g);
        add8(A, ua0); add8(A, ua1);
        add8(B, ub0); add8(B, ub1);
        qa = qa_n; qb = qb_n;
    }
}

// combine groups, scale by dinv[d], + bias, relu
__device__ __forceinline__ void combine_scale(float dv, const float* bias, int r,
                                              float* acc) {
#pragma unroll
    for (int j = 0; j < 8; j++) {
        acc[j] += __shfl_xor(acc[j], 16, 64);
        acc[j] += __shfl_xor(acc[j], 32, 64);
    }
    float4 b0 = ((const float4*)bias)[2 * r];
    float4 b1 = ((const float4*)bias)[2 * r + 1];
    acc[0] = fmaxf(fmaf(dv, acc[0], b0.x), 0.f);
    acc[1] = fmaxf(fmaf(dv, acc[1], b0.y), 0.f);
    acc[2] = fmaxf(fmaf(dv, acc[2], b0.z), 0.f);
    acc[3] = fmaxf(fmaf(dv, acc[3], b0.w), 0.f);
    acc[4] = fmaxf(fmaf(dv, acc[4], b1.x), 0.f);
    acc[5] = fmaxf(fmaf(dv, acc[5], b1.y), 0.f);
    acc[6] = fmaxf(fmaf(dv, acc[6], b1.z), 0.f);
    acc[7] = fmaxf(fmaf(dv, acc[7], b1.w), 0.f);
}

// ---- fused: h = relu(dv*agg+b) -> LDS tile -> hw_out = dinv * (h @ W) ------
__global__ __launch_bounds__(256) void k_agg_gemm(const u16* __restrict__ hw_in,
                                                  const int* __restrict__ rp8,
                                                  const int* __restrict__ recs,
                                                  const float* __restrict__ dinv,
                                                  const float* __restrict__ bias,
                                                  const u16* __restrict__ Wt,
                                                  u16* __restrict__ hw_out) {
    __shared__ u16 sm[16 * ROWW];
    int lane = threadIdx.x & 63;
    int w = threadIdx.x >> 6;
    int g = lane >> 4, r = lane & 15;
    int base = blockIdx.x * 16;
#pragma unroll
    for (int p = 0; p < 2; p++) {
        int rowa = w * 4 + 2 * p;
        int va = base + rowa;
        float A[8], B[8];
        agg_pair(hw_in, rp8, recs, va, va + 1, g, r, A, B);
        combine_scale(dinv[va], bias, r, A);
        combine_scale(dinv[va + 1], bias, r, B);
        if (g == 0) {
            uint4 pk;
            pk.x = (u32)f2bf(A[0]) | ((u32)f2bf(A[1]) << 16);
            pk.y = (u32)f2bf(A[2]) | ((u32)f2bf(A[3]) << 16);
            pk.z = (u32)f2bf(A[4]) | ((u32)f2bf(A[5]) << 16);
            pk.w = (u32)f2bf(A[6]) | ((u32)f2bf(A[7]) << 16);
            *(uint4*)(sm + rowa * ROWW + r * 8) = pk;
            pk.x = (u32)f2bf(B[0]) | ((u32)f2bf(B[1]) << 16);
            pk.y = (u32)f2bf(B[2]) | ((u32)f2bf(B[3]) << 16);
            pk.z = (u32)f2bf(B[4]) | ((u32)f2bf(B[5]) << 16);
            pk.w = (u32)f2bf(B[6]) | ((u32)f2bf(B[7]) << 16);
            *(uint4*)(sm + (rowa + 1) * ROWW + r * 8) = pk;
        }
    }
    __syncthreads();
    // GEMM: 16x128 LDS tile @ 128x128 W; wave w does n-tiles {2w, 2w+1}
    int q = lane >> 4;
    bf16x8 Af[4];
#pragma unroll
    for (int kc = 0; kc < 4; kc++)
        Af[kc] = *(const bf16x8*)(sm + r * ROWW + kc * 32 + q * 8);
    float dv[4];
#pragma unroll
    for (int i = 0; i < 4; i++) dv[i] = dinv[base + q * 4 + i];
#pragma unroll
    for (int t = 0; t < 2; t++) {
        int nt = w * 2 + t;
        f32x4 acc = {0.f, 0.f, 0.f, 0.f};
#pragma unroll
        for (int kc = 0; kc < 4; kc++) {
            bf16x8 Bf = *(const bf16x8*)(Wt + ((nt * 16 + r) << 7) + kc * 32 + q * 8);
            acc = __builtin_amdgcn_mfma_f32_16x16x32_bf16(Af[kc], Bf, acc, 0, 0, 0);
        }
#pragma unroll
        for (int i = 0; i < 4; i++)
            hw_out[(size_t)(base + q * 4 + i) * DIM + nt * 16 + r] = f2bf(dv[i] * acc[i]);
    }
}

// ---- final layer: relu(dv*agg+b) -> f32 out, 2 nodes per wave --------------
__global__ __launch_bounds__(256) void k_agg_out(const u16* __restrict__ hw_in,
                                                 const int* __restrict__ rp8,
                                                 const int* __restrict__ recs,
                                                 const float* __restrict__ dinv,
                                                 const float* __restrict__ bias,
                                                 float* __restrict__ out) {
    int lane = threadIdx.x & 63;
    int w = threadIdx.x >> 6;
    int g = lane >> 4, r = lane & 15;
    int va = blockIdx.x * 8 + w * 2;  // grid 6250 exact
    float A[8], B[8];
    agg_pair(hw_in, rp8, recs, va, va + 1, g, r, A, B);
    combine_scale(dinv[va], bias, r, A);
    combine_scale(dinv[va + 1], bias, r, B);
    if (g == 0) {
        float4* p = (float4*)(out + (size_t)va * DIM + r * 8);
        p[0] = make_float4(A[0], A[1], A[2], A[3]);
        p[1] = make_float4(A[4], A[5], A[6], A[7]);
        p = (float4*)(out + (size_t)(va + 1) * DIM + r * 8);
        p[0] = make_float4(B[0], B[1], B[2], B[3]);
        p[1] = make_float4(B[4], B[5], B[6], B[7]);
    }
}

// ---- launch ----------------------------------------------------------------

extern "C" void kernel_launch(void* const* d_in, const int* in_sizes, int n_in,
                              void* d_out, int out_size, void* d_ws, size_t ws_size,
                              hipStream_t stream) {
    const float* x = (const float*)d_in[0];
    const int* ei = (const int*)d_in[1];
    const float* W0 = (const float*)d_in[2];
    const float* b0 = (const float*)d_in[3];
    const float* W1 = (const float*)d_in[4];
    const float* b1 = (const float*)d_in[5];
    const float* W2 = (const float*)d_in[6];
    const float* b2 = (const float*)d_in[7];

    char* ws = (char*)d_ws;
    size_t off = 0;
    auto alloc = [&](size_t bytes) -> void* {
        void* p = ws + off;
        off += (bytes + 511) & ~(size_t)511;
        return p;
    };
    int* deg = (int*)alloc(NN * 4);      // zeroed
    int* cursor = (int*)alloc(NN * 4);   // zeroed
    size_t zbytes = off;
    int* recs = (int*)alloc((size_t)NEPAD * 4);
    float* dinv = (float*)alloc(NN * 4);
    int* rp8 = (int*)alloc((NN + 1) * 4);
    u16* Wt = (u16*)alloc(3 * 128 * 128 * 2);
    u16* hwA = (u16*)alloc((size_t)(NN + 1) * DIM * 2);  // +1 sentinel row
    u16* hwB = (u16*)alloc((size_t)(NN + 1) * DIM * 2);

    hipMemsetAsync(ws, 0, zbytes, stream);
    k_count<<<NB_E, 256, 0, stream>>>(ei, deg);
    k_scan<<<1, 1024, 0, stream>>>(deg, rp8, dinv);
    k_fill<<<NB_E, 256, 0, stream>>>(ei, rp8, cursor, deg, recs,
                                     W0, W1, W2, Wt, hwA, hwB);
    k_gemm_f32<<<(TILES + 3) / 4, 256, 0, stream>>>(x, Wt, dinv, hwA);
    k_agg_gemm<<<TILES, 256, 0, stream>>>(hwA, rp8, recs, dinv, b0,
                                          Wt + 16384, hwB);
    k_agg_gemm<<<TILES, 256, 0, stream>>>(hwB, rp8, recs, dinv, b1,
                                          Wt + 32768, hwA);
    k_agg_out<<<6250, 256, 0, stream>>>(hwA, rp8, recs, dinv, b2,
                                        (float*)d_out);
}

// Round 8
// 272.901 us; speedup vs baseline: 1.3749x; 1.3749x over previous
//
#include <hip/hip_runtime.h>

#define NN 50000
#define NE 600000
#define DIM 128
#define NB_N 196   // ceil(50000/256)
#define NB_E 2344  // ceil(600000/256)
#define TILES 3125 // 50000/16
#define ROWW 136   // LDS row pitch in u16 (128 + 8 pad)
#define NEPAD (NE + 8 * NN + 64)  // rows padded to multiple of 8, min 8

typedef unsigned short u16;
typedef unsigned int u32;
typedef __attribute__((ext_vector_type(8))) short bf16x8;
typedef __attribute__((ext_vector_type(4))) float f32x4;

__device__ __forceinline__ u16 f2bf(float f) {
    u32 u = __builtin_bit_cast(u32, f);
    u32 r = (u + 0x7FFFu + ((u >> 16) & 1u)) >> 16;
    return (u16)r;
}
__device__ __forceinline__ float bflo(u32 w) { return __builtin_bit_cast(float, w << 16); }
__device__ __forceinline__ float bfhi(u32 w) { return __builtin_bit_cast(float, w & 0xffff0000u); }
__device__ __forceinline__ int pad8(int d) {
    int p = (d + 7) & ~7;
    return p < 8 ? 8 : p;
}

// ---- CSR build -------------------------------------------------------------

__global__ __launch_bounds__(256) void k_count(const int* __restrict__ ei,
                                               int* __restrict__ deg) {
    __shared__ int s64;
    if (threadIdx.x == 0) {
        int o = 0;
#pragma unroll
        for (int j = 0; j < 16; j++) o |= ei[2 * j + 1];  // int64 => high words 0
        s64 = (o == 0);
    }
    __syncthreads();
    int e = blockIdx.x * 256 + threadIdx.x;
    if (e >= NE) return;
    int d = s64 ? ei[2 * (NE + e)] : ei[NE + e];
    atomicAdd(&deg[d], 1);
}

// exclusive scan of pad8(deg) -> rp8 (two-level, multi-block)
__global__ __launch_bounds__(256) void k_scanA(const int* __restrict__ deg,
                                               int* __restrict__ rp8,
                                               int* __restrict__ bsum) {
    __shared__ int buf[256];
    int t = threadIdx.x, i = blockIdx.x * 256 + t;
    int v = (i < NN) ? pad8(deg[i]) : 0;
    buf[t] = v;
    __syncthreads();
    for (int off = 1; off < 256; off <<= 1) {
        int x = (t >= off) ? buf[t - off] : 0;
        __syncthreads();
        buf[t] += x;
        __syncthreads();
    }
    if (i < NN) rp8[i] = buf[t] - v;
    if (t == 255) bsum[blockIdx.x] = buf[255];
}

__global__ __launch_bounds__(256) void k_scanB(int* __restrict__ bsum) {
    __shared__ int buf[256];
    int t = threadIdx.x;
    int v = (t < NB_N) ? bsum[t] : 0;
    buf[t] = v;
    __syncthreads();
    for (int off = 1; off < 256; off <<= 1) {
        int x = (t >= off) ? buf[t - off] : 0;
        __syncthreads();
        buf[t] += x;
        __syncthreads();
    }
    bsum[t] = buf[t] - v;
}

__global__ __launch_bounds__(256) void k_scanC(const int* __restrict__ deg,
                                               int* __restrict__ rp8,
                                               const int* __restrict__ bsum,
                                               float* __restrict__ dinv) {
    int i = blockIdx.x * 256 + threadIdx.x;
    if (i < NN) {
        rp8[i] += bsum[i >> 8];
        dinv[i] = rsqrtf((float)(deg[i] + 1));  // +1 self loop
    }
    if (i == 0) rp8[NN] = bsum[255];
}

// fill CSR (src only, 4 B) + secondary work: wcast, pad entries -> NN, zero
// sentinel rows of hwA/hwB
__global__ __launch_bounds__(256) void k_fill(const int* __restrict__ ei,
                                              const int* __restrict__ rp8,
                                              int* __restrict__ cursor,
                                              const int* __restrict__ deg,
                                              int* __restrict__ recs,
                                              const float* __restrict__ W0,
                                              const float* __restrict__ W1,
                                              const float* __restrict__ W2,
                                              u16* __restrict__ Wt,
                                              u16* __restrict__ hwA,
                                              u16* __restrict__ hwB) {
    __shared__ int s64;
    if (threadIdx.x == 0) {
        int o = 0;
#pragma unroll
        for (int j = 0; j < 16; j++) o |= ei[2 * j + 1];
        s64 = (o == 0);
    }
    __syncthreads();
    int e = blockIdx.x * 256 + threadIdx.x;
    if (e < NE) {
        int is64 = s64;
        int s = is64 ? ei[2 * e] : ei[e];
        int d = is64 ? ei[2 * (NE + e)] : ei[NE + e];
        int pos = rp8[d] + atomicAdd(&cursor[d], 1);
        recs[pos] = s;
    }
    // secondary roles
    int b = blockIdx.x;
    if (b < 192) {  // weight cast: Wt[layer][n][k] = bf16(W[layer][k][n])
        int idx = b * 256 + threadIdx.x;  // < 49152 = 3*16384
        int l = idx >> 14, rem = idx & 16383;
        int n = rem >> 7, k = rem & 127;
        const float* W = (l == 0) ? W0 : ((l == 1) ? W1 : W2);
        Wt[idx] = f2bf(W[k * 128 + n]);
    } else if (b < 388) {  // pad entries -> sentinel row NN
        int i = (b - 192) * 256 + threadIdx.x;
        if (i < NN) {
            int rp = rp8[i], d = deg[i], p = pad8(d);
            for (int j = d; j < p; j++) recs[rp + j] = NN;
        }
    } else if (b == 388) {  // zero sentinel rows (256 B each)
        if (threadIdx.x < 64) {
            ((u32*)(hwA + (size_t)NN * DIM))[threadIdx.x] = 0;
            ((u32*)(hwB + (size_t)NN * DIM))[threadIdx.x] = 0;
        }
    }
}

// ---- layer-1 GEMM: hw'[v] = dinv[v] * (bf16(x) @ W0) -----------------------
__global__ __launch_bounds__(256) void k_gemm_f32(const float* __restrict__ x,
                                                  const u16* __restrict__ Wt,
                                                  const float* __restrict__ dinv,
                                                  u16* __restrict__ hwb) {
    int lane = threadIdx.x & 63;
    int tile = blockIdx.x * 4 + (threadIdx.x >> 6);
    if (tile >= TILES) return;
    int r = lane & 15, q = lane >> 4;

    bf16x8 Bf[8][4];
#pragma unroll
    for (int nt = 0; nt < 8; nt++)
#pragma unroll
        for (int kc = 0; kc < 4; kc++)
            Bf[nt][kc] = *(const bf16x8*)(Wt + ((nt * 16 + r) << 7) + kc * 32 + q * 8);

    long rowbase = (long)tile * 16;
    bf16x8 Af[4];
#pragma unroll
    for (int kc = 0; kc < 4; kc++) {
        const float4* p = (const float4*)(x + (rowbase + r) * 128 + kc * 32 + q * 8);
        float4 t0 = p[0], t1 = p[1];
        bf16x8 a;
        a[0] = (short)f2bf(t0.x); a[1] = (short)f2bf(t0.y);
        a[2] = (short)f2bf(t0.z); a[3] = (short)f2bf(t0.w);
        a[4] = (short)f2bf(t1.x); a[5] = (short)f2bf(t1.y);
        a[6] = (short)f2bf(t1.z); a[7] = (short)f2bf(t1.w);
        Af[kc] = a;
    }

    float dv[4];
#pragma unroll
    for (int i = 0; i < 4; i++) dv[i] = dinv[rowbase + q * 4 + i];

#pragma unroll
    for (int nt = 0; nt < 8; nt++) {
        f32x4 acc = {0.f, 0.f, 0.f, 0.f};
#pragma unroll
        for (int kc = 0; kc < 4; kc++)
            acc = __builtin_amdgcn_mfma_f32_16x16x32_bf16(Af[kc], Bf[nt][kc], acc, 0, 0, 0);
#pragma unroll
        for (int i = 0; i < 4; i++)
            hwb[(rowbase + q * 4 + i) * 128 + nt * 16 + r] = f2bf(dv[i] * acc[i]);
    }
}

// ---- aggregation core: wave = 2 nodes interleaved; group g handles edges
// {e+2g, e+2g+1}; lane r=lane&15 holds feats 8r..8r+7. Pure adds (no norms):
// pads & clamped re-reads read sentinel row NN (zeros).
__device__ __forceinline__ void add8(float* a, uint4 u) {
    a[0] += bflo(u.x); a[1] += bfhi(u.x);
    a[2] += bflo(u.y); a[3] += bfhi(u.y);
    a[4] += bflo(u.z); a[5] += bfhi(u.z);
    a[6] += bflo(u.w); a[7] += bfhi(u.w);
}

__device__ __forceinline__ void agg_pair(const u16* __restrict__ hw,
                                         const int* __restrict__ rp8,
                                         const int* __restrict__ recs,
                                         int va, int vb, int g, int r,
                                         float* A, float* B) {
    uint4 sva = *(const uint4*)(hw + (size_t)va * DIM + r * 8);
    uint4 svb = *(const uint4*)(hw + (size_t)vb * DIM + r * 8);
    float m = (g == 0) ? 1.0f : 0.0f;  // self term counted once
    A[0] = m * bflo(sva.x); A[1] = m * bfhi(sva.x);
    A[2] = m * bflo(sva.y); A[3] = m * bfhi(sva.y);
    A[4] = m * bflo(sva.z); A[5] = m * bfhi(sva.z);
    A[6] = m * bflo(sva.w); A[7] = m * bfhi(sva.w);
    B[0] = m * bflo(svb.x); B[1] = m * bfhi(svb.x);
    B[2] = m * bflo(svb.y); B[3] = m * bfhi(svb.y);
    B[4] = m * bflo(svb.z); B[5] = m * bfhi(svb.z);
    B[6] = m * bflo(svb.w); B[7] = m * bfhi(svb.w);

    int ea = rp8[va], enda = rp8[va + 1];
    int eb = rp8[vb], endb = rp8[vb + 1];
    int2 qa = *(const int2*)(recs + ea + 2 * g);
    int2 qb = *(const int2*)(recs + eb + 2 * g);
    while (ea < enda || eb < endb) {
        int sa0 = (ea < enda) ? qa.x : NN;
        int sa1 = (ea < enda) ? qa.y : NN;
        int sb0 = (eb < endb) ? qb.x : NN;
        int sb1 = (eb < endb) ? qb.y : NN;
        uint4 ua0 = *(const uint4*)(hw + (size_t)(u32)sa0 * DIM + r * 8);
        uint4 ua1 = *(const uint4*)(hw + (size_t)(u32)sa1 * DIM + r * 8);
        uint4 ub0 = *(const uint4*)(hw + (size_t)(u32)sb0 * DIM + r * 8);
        uint4 ub1 = *(const uint4*)(hw + (size_t)(u32)sb1 * DIM + r * 8);
        ea += 8; eb += 8;
        int2 qa_n = *(const int2*)(recs + min(ea, enda - 8) + 2 * g);
        int2 qb_n = *(const int2*)(recs + min(eb, endb - 8) + 2 * g);
        add8(A, ua0); add8(A, ua1);
        add8(B, ub0); add8(B, ub1);
        qa = qa_n; qb = qb_n;
    }
}

// combine groups, scale by dinv[d], + bias, relu
__device__ __forceinline__ void combine_scale(float dv, const float* bias, int r,
                                              float* acc) {
#pragma unroll
    for (int j = 0; j < 8; j++) {
        acc[j] += __shfl_xor(acc[j], 16, 64);
        acc[j] += __shfl_xor(acc[j], 32, 64);
    }
    float4 b0 = ((const float4*)bias)[2 * r];
    float4 b1 = ((const float4*)bias)[2 * r + 1];
    acc[0] = fmaxf(fmaf(dv, acc[0], b0.x), 0.f);
    acc[1] = fmaxf(fmaf(dv, acc[1], b0.y), 0.f);
    acc[2] = fmaxf(fmaf(dv, acc[2], b0.z), 0.f);
    acc[3] = fmaxf(fmaf(dv, acc[3], b0.w), 0.f);
    acc[4] = fmaxf(fmaf(dv, acc[4], b1.x), 0.f);
    acc[5] = fmaxf(fmaf(dv, acc[5], b1.y), 0.f);
    acc[6] = fmaxf(fmaf(dv, acc[6], b1.z), 0.f);
    acc[7] = fmaxf(fmaf(dv, acc[7], b1.w), 0.f);
}

// ---- fused: h = relu(dv*agg+b) -> LDS tile -> hw_out = dinv * (h @ W) ------
__global__ __launch_bounds__(256) void k_agg_gemm(const u16* __restrict__ hw_in,
                                                  const int* __restrict__ rp8,
                                                  const int* __restrict__ recs,
                                                  const float* __restrict__ dinv,
                                                  const float* __restrict__ bias,
                                                  const u16* __restrict__ Wt,
                                                  u16* __restrict__ hw_out) {
    __shared__ u16 sm[16 * ROWW];
    int lane = threadIdx.x & 63;
    int w = threadIdx.x >> 6;
    int g = lane >> 4, r = lane & 15;
    int base = blockIdx.x * 16;
#pragma unroll
    for (int p = 0; p < 2; p++) {
        int rowa = w * 4 + 2 * p;
        int va = base + rowa;
        float A[8], B[8];
        agg_pair(hw_in, rp8, recs, va, va + 1, g, r, A, B);
        combine_scale(dinv[va], bias, r, A);
        combine_scale(dinv[va + 1], bias, r, B);
        if (g == 0) {
            uint4 pk;
            pk.x = (u32)f2bf(A[0]) | ((u32)f2bf(A[1]) << 16);
            pk.y = (u32)f2bf(A[2]) | ((u32)f2bf(A[3]) << 16);
            pk.z = (u32)f2bf(A[4]) | ((u32)f2bf(A[5]) << 16);
            pk.w = (u32)f2bf(A[6]) | ((u32)f2bf(A[7]) << 16);
            *(uint4*)(sm + rowa * ROWW + r * 8) = pk;
            pk.x = (u32)f2bf(B[0]) | ((u32)f2bf(B[1]) << 16);
            pk.y = (u32)f2bf(B[2]) | ((u32)f2bf(B[3]) << 16);
            pk.z = (u32)f2bf(B[4]) | ((u32)f2bf(B[5]) << 16);
            pk.w = (u32)f2bf(B[6]) | ((u32)f2bf(B[7]) << 16);
            *(uint4*)(sm + (rowa + 1) * ROWW + r * 8) = pk;
        }
    }
    __syncthreads();
    // GEMM: 16x128 LDS tile @ 128x128 W; wave w does n-tiles {2w, 2w+1}
    int q = lane >> 4;
    bf16x8 Af[4];
#pragma unroll
    for (int kc = 0; kc < 4; kc++)
        Af[kc] = *(const bf16x8*)(sm + r * ROWW + kc * 32 + q * 8);
    float dv[4];
#pragma unroll
    for (int i = 0; i < 4; i++) dv[i] = dinv[base + q * 4 + i];
#pragma unroll
    for (int t = 0; t < 2; t++) {
        int nt = w * 2 + t;
        f32x4 acc = {0.f, 0.f, 0.f, 0.f};
#pragma unroll
        for (int kc = 0; kc < 4; kc++) {
            bf16x8 Bf = *(const bf16x8*)(Wt + ((nt * 16 + r) << 7) + kc * 32 + q * 8);
            acc = __builtin_amdgcn_mfma_f32_16x16x32_bf16(Af[kc], Bf, acc, 0, 0, 0);
        }
#pragma unroll
        for (int i = 0; i < 4; i++)
            hw_out[(size_t)(base + q * 4 + i) * DIM + nt * 16 + r] = f2bf(dv[i] * acc[i]);
    }
}

// ---- final layer: relu(dv*agg+b) -> f32 out, 2 nodes per wave --------------
__global__ __launch_bounds__(256) void k_agg_out(const u16* __restrict__ hw_in,
                                                 const int* __restrict__ rp8,
                                                 const int* __restrict__ recs,
                                                 const float* __restrict__ dinv,
                                                 const float* __restrict__ bias,
                                                 float* __restrict__ out) {
    int lane = threadIdx.x & 63;
    int w = threadIdx.x >> 6;
    int g = lane >> 4, r = lane & 15;
    int va = blockIdx.x * 8 + w * 2;  // grid 6250 exact
    float A[8], B[8];
    agg_pair(hw_in, rp8, recs, va, va + 1, g, r, A, B);
    combine_scale(dinv[va], bias, r, A);
    combine_scale(dinv[va + 1], bias, r, B);
    if (g == 0) {
        float4* p = (float4*)(out + (size_t)va * DIM + r * 8);
        p[0] = make_float4(A[0], A[1], A[2], A[3]);
        p[1] = make_float4(A[4], A[5], A[6], A[7]);
        p = (float4*)(out + (size_t)(va + 1) * DIM + r * 8);
        p[0] = make_float4(B[0], B[1], B[2], B[3]);
        p[1] = make_float4(B[4], B[5], B[6], B[7]);
    }
}

// ---- launch ----------------------------------------------------------------

extern "C" void kernel_launch(void* const* d_in, const int* in_sizes, int n_in,
                              void* d_out, int out_size, void* d_ws, size_t ws_size,
                              hipStream_t stream) {
    const float* x = (const float*)d_in[0];
    const int* ei = (const int*)d_in[1];
    const float* W0 = (const float*)d_in[2];
    const float* b0 = (const float*)d_in[3];
    const float* W1 = (const float*)d_in[4];
    const float* b1 = (const float*)d_in[5];
    const float* W2 = (const float*)d_in[6];
    const float* b2 = (const float*)d_in[7];

    char* ws = (char*)d_ws;
    size_t off = 0;
    auto alloc = [&](size_t bytes) -> void* {
        void* p = ws + off;
        off += (bytes + 511) & ~(size_t)511;
        return p;
    };
    int* deg = (int*)alloc(NN * 4);      // zeroed
    int* cursor = (int*)alloc(NN * 4);   // zeroed
    size_t zbytes = off;
    int* recs = (int*)alloc((size_t)NEPAD * 4);
    float* dinv = (float*)alloc(NN * 4);
    int* rp8 = (int*)alloc((NN + 1) * 4);
    int* bsum = (int*)alloc(256 * 4);
    u16* Wt = (u16*)alloc(3 * 128 * 128 * 2);
    u16* hwA = (u16*)alloc((size_t)(NN + 1) * DIM * 2);  // +1 sentinel row
    u16* hwB = (u16*)alloc((size_t)(NN + 1) * DIM * 2);

    hipMemsetAsync(ws, 0, zbytes, stream);
    k_count<<<NB_E, 256, 0, stream>>>(ei, deg);
    k_scanA<<<NB_N, 256, 0, stream>>>(deg, rp8, bsum);
    k_scanB<<<1, 256, 0, stream>>>(bsum);
    k_scanC<<<NB_N, 256, 0, stream>>>(deg, rp8, bsum, dinv);
    k_fill<<<NB_E, 256, 0, stream>>>(ei, rp8, cursor, deg, recs,
                                     W0, W1, W2, Wt, hwA, hwB);
    k_gemm_f32<<<(TILES + 3) / 4, 256, 0, stream>>>(x, Wt, dinv, hwA);
    k_agg_gemm<<<TILES, 256, 0, stream>>>(hwA, rp8, recs, dinv, b0,
                                          Wt + 16384, hwB);
    k_agg_gemm<<<TILES, 256, 0, stream>>>(hwB, rp8, recs, dinv, b1,
                                          Wt + 32768, hwA);
    k_agg_out<<<6250, 256, 0, stream>>>(hwA, rp8, recs, dinv, b2,
                                        (float*)d_out);
}